// Round 2
// baseline (38.495 us; speedup 1.0000x reference)
//
#include <hip/hip_runtime.h>

// ---- problem constants ----
#define B_TOK   128
#define E_TOP   4
#define NEXP    32
#define KDIM    512
#define CDIM    1024
#define PAIRS   (B_TOK * E_TOP)   // 512
#define HALF_C  (CDIM / 2)        // 512

#define ALPHA   1.702f
#define LIMIT   7.0f

// ---- tiling ----
#define CH      64                // channels per block
#define TT      16                // tokens per chunk
#define NQ      4                 // k-split: 4 quarters, one wave each
#define KQ      (KDIM / NQ)       // 128 k per quarter
#define KT      16                // k per stage step
#define NSTEP   (KQ / KT)         // 8 steps per quarter

// =====================================================================
// Kernel 1: bucket (b,e) assignments by expert. Order-independent output.
// =====================================================================
__global__ void bucket_kernel(const int* __restrict__ idx,
                              unsigned short* __restrict__ lists,
                              int* __restrict__ counts) {
    __shared__ int cnt[NEXP];
    const int t = threadIdx.x;            // 0..511
    if (t < NEXP) cnt[t] = 0;
    __syncthreads();
    const int e = idx[t];
    const int pos = atomicAdd(&cnt[e], 1);
    lists[e * PAIRS + pos] = (unsigned short)t;
    __syncthreads();
    if (t < NEXP) counts[t] = cnt[t];
}

__device__ __forceinline__ float glu_act(float g, float l) {
    g = fminf(g, LIMIT);
    l = fminf(fmaxf(l, -LIMIT), LIMIT);
    const float sg = 1.0f / (1.0f + __expf(-ALPHA * g));
    return (g * sg) * (l + 1.0f);
}

// pack two f32 -> one dword of 2 bf16 (RNE), lo = first
__device__ __forceinline__ unsigned pack_bf16(float a, float b) {
    unsigned ua = __float_as_uint(a);
    unsigned ub = __float_as_uint(b);
    ua = (ua + 0x7FFFu + ((ua >> 16) & 1u)) >> 16;
    ub = (ub + 0x7FFFu + ((ub >> 16) & 1u)) & 0xFFFF0000u;
    return ua | ub;
}
__device__ __forceinline__ float bflo(unsigned u) { return __uint_as_float(u << 16); }
__device__ __forceinline__ float bfhi(unsigned u) { return __uint_as_float(u & 0xFFFF0000u); }

// =====================================================================
// Kernel 2: block = (expert, 64-channel chunk, z). 256 threads = 4 waves,
// each wave owns one K-quarter with a wave-private double-buffered W tile
// staged via global_load_lds -> NO barriers in the K-loop, only counted
// vmcnt waits. x is staged once per chunk as packed bf16 [k/2][t].
// Thread tile: 4 tokens x 4 channels, fp32 accumulation.
// =====================================================================
__global__ __launch_bounds__(256, 3) void moe_mlp1_kernel(
    const float* __restrict__ x,      // [128, 512]
    const float* __restrict__ w,      // [32, 1024, 512]
    const float* __restrict__ bias,   // [32, 1024]
    const unsigned short* __restrict__ lists,
    const int* __restrict__ counts,
    float* __restrict__ out)          // [512, 512] fp32
{
    __shared__ unsigned xs[(KDIM / 2) * TT];   // 256*16 dwords = 16 KB (also reduce buf)
    __shared__ float wbuf[NQ][2][CH * KT];     // 4*2*4KB = 32 KB

    const int tid   = threadIdx.x;
    const int e     = blockIdx.y;
    const int cBase = blockIdx.x * CH;
    const int T     = counts[e];

    const int q    = tid >> 6;          // k-quarter (= wave id)
    const int lane = tid & 63;
    const int t0   = (lane & 3) * 4;    // token sub-tile base
    const int c0   = (lane >> 2) * 4;   // channel sub-tile base (0..60)
    const int sw   = (lane >> 2) & 3;   // read-side XOR swizzle = ((c0)>>2)&3

    // W stage source (pre-swizzled global so linear LDS write lands swizzled):
    // lane covers phys row c = i*16 + (lane>>2), phys slot = lane&3,
    // logical slot = (lane&3) ^ swz(c),  swz(c) = (c>>2)&3 = (lane>>4)&3
    const int srow  = lane >> 2;                 // 0..15
    const int sslot = (lane & 3) ^ (lane >> 4);  // logical float4-slot to fetch
    const float* wq = w + ((size_t)e * CDIM + cBase) * KDIM + q * KQ;

    for (int chunk = blockIdx.z; chunk * TT < T; chunk += 2) {
        const int tBase = chunk * TT;
        const int nT    = min(TT, T - tBase);

        __syncthreads();   // xs (incl. reduce overlay) free to overwrite

        // ---- stage x chunk: packed bf16, layout [k/2][t] ----
        {
            const int tok  = tid & 15;
            const int kq16 = tid >> 4;            // 0..15 -> k in [kq16*32, +32)
            const bool v   = tok < nT;
            int pairIdx = 0;
            if (v) pairIdx = (int)lists[e * PAIRS + tBase + tok];
            const int brow = pairIdx >> 2;
            const float4* xr = (const float4*)(x + (size_t)brow * KDIM + kq16 * 32);
            #pragma unroll
            for (int r = 0; r < 8; ++r) {
                float4 f = v ? xr[r] : make_float4(0.f, 0.f, 0.f, 0.f);
                const int k2 = kq16 * 16 + r * 2;
                xs[(k2 + 0) * TT + tok] = pack_bf16(f.x, f.y);
                xs[(k2 + 1) * TT + tok] = pack_bf16(f.z, f.w);
            }
        }
        __syncthreads();   // xs ready (compiler drains vmcnt/lgkm here)

        float acc[4][4];
        #pragma unroll
        for (int j = 0; j < 4; ++j)
            #pragma unroll
            for (int i = 0; i < 4; ++i) acc[j][i] = 0.f;

        // ---- wave-private W staging (4 x global_load_lds of 16B = 1 tile) ----
        auto stage = [&](int s, int pb) {
            float* dst = &wbuf[q][pb][0];
            const float* srcb = wq + (size_t)srow * KDIM + s * KT + sslot * 4;
            #pragma unroll
            for (int i = 0; i < 4; ++i) {
                __builtin_amdgcn_global_load_lds(
                    (const __attribute__((address_space(1))) void*)(srcb + (size_t)i * 16 * KDIM),
                    (__attribute__((address_space(3))) void*)(dst + i * 256),
                    16, 0, 0);
            }
        };

        auto compute = [&](int s, int pb) {
            const float* wb = &wbuf[q][pb][0];
            const int k2base = q * (KQ / 2) + s * (KT / 2);   // dword-row in xs
            #pragma unroll
            for (int k4 = 0; k4 < 4; ++k4) {                  // 4 k's per group
                const uint4 xp0 = *(const uint4*)&xs[(k2base + k4 * 2 + 0) * TT + t0];
                const uint4 xp1 = *(const uint4*)&xs[(k2base + k4 * 2 + 1) * TT + t0];
                const int pslot = ((k4 ^ sw) << 2);
                float4 wv[4];
                #pragma unroll
                for (int i = 0; i < 4; ++i)
                    wv[i] = *(const float4*)&wb[(c0 + i) * KT + pslot];
                const unsigned xd[8] = {xp0.x, xp0.y, xp0.z, xp0.w,
                                        xp1.x, xp1.y, xp1.z, xp1.w};
                #pragma unroll
                for (int j = 0; j < 4; ++j) {
                    const float xf0 = bflo(xd[j]),     xf1 = bfhi(xd[j]);
                    const float xf2 = bflo(xd[4 + j]), xf3 = bfhi(xd[4 + j]);
                    #pragma unroll
                    for (int i = 0; i < 4; ++i) {
                        acc[j][i] = fmaf(xf0, wv[i].x, acc[j][i]);
                        acc[j][i] = fmaf(xf1, wv[i].y, acc[j][i]);
                        acc[j][i] = fmaf(xf2, wv[i].z, acc[j][i]);
                        acc[j][i] = fmaf(xf3, wv[i].w, acc[j][i]);
                    }
                }
            }
        };

        // ---- barrier-free K-loop: prefetch depth 1, counted vmcnt ----
        stage(0, 0);
        for (int s = 0; s < NSTEP - 1; ++s) {
            __builtin_amdgcn_sched_barrier(0);
            stage(s + 1, (s + 1) & 1);
            asm volatile("s_waitcnt vmcnt(4)" ::: "memory");  // tile s landed
            __builtin_amdgcn_sched_barrier(0);
            compute(s, s & 1);
        }
        __builtin_amdgcn_sched_barrier(0);
        asm volatile("s_waitcnt vmcnt(0)" ::: "memory");
        __builtin_amdgcn_sched_barrier(0);
        compute(NSTEP - 1, (NSTEP - 1) & 1);

        // ---- 4-way k-split combine through LDS (overlay on xs) ----
        __syncthreads();
        if (q != 0) {
            float4* red = (float4*)xs;
            #pragma unroll
            for (int j = 0; j < 4; ++j)
                red[((q - 1) * 64 + lane) * 4 + j] =
                    make_float4(acc[j][0], acc[j][1], acc[j][2], acc[j][3]);
        }
        __syncthreads();
        if (q == 0) {
            const float4* red = (const float4*)xs;
            #pragma unroll
            for (int r = 0; r < 3; ++r)
                #pragma unroll
                for (int j = 0; j < 4; ++j) {
                    const float4 p = red[(r * 64 + lane) * 4 + j];
                    acc[j][0] += p.x; acc[j][1] += p.y;
                    acc[j][2] += p.z; acc[j][3] += p.w;
                }
            const float4 bv = *(const float4*)(bias + (size_t)e * CDIM + cBase + c0);
            #pragma unroll
            for (int j = 0; j < 4; ++j) {
                const int tl = t0 + j;
                if (tl < nT) {
                    const int pairIdx = (int)lists[e * PAIRS + tBase + tl];
                    const float g0 = acc[j][0] + bv.x, l0 = acc[j][1] + bv.y;
                    const float g1 = acc[j][2] + bv.z, l1 = acc[j][3] + bv.w;
                    float2 o;
                    o.x = glu_act(g0, l0);
                    o.y = glu_act(g1, l1);
                    *(float2*)&out[(size_t)pairIdx * HALF_C + ((cBase + c0) >> 1)] = o;
                }
            }
        }
    }
}

extern "C" void kernel_launch(void* const* d_in, const int* in_sizes, int n_in,
                              void* d_out, int out_size, void* d_ws, size_t ws_size,
                              hipStream_t stream) {
    const float* x    = (const float*)d_in[0];
    const int*   idx  = (const int*)d_in[1];
    const float* w    = (const float*)d_in[2];
    const float* bias = (const float*)d_in[3];
    float* out = (float*)d_out;

    unsigned short* lists = (unsigned short*)d_ws;
    int* counts = (int*)((char*)d_ws + NEXP * PAIRS * sizeof(unsigned short));

    bucket_kernel<<<1, PAIRS, 0, stream>>>(idx, lists, counts);

    dim3 grid(CDIM / CH, NEXP, 2);    // (16, 32, 2) = 1024 blocks
    moe_mlp1_kernel<<<grid, 256, 0, stream>>>(x, w, bias, lists, counts, out);
}